// Round 1
// baseline (1591.473 us; speedup 1.0000x reference)
//
#include <hip/hip_runtime.h>
#include <hip/hip_bf16.h>
#include <math.h>

#define TID threadIdx.x

constexpr int Cc = 512, Tt = 1024, C3 = 1536;

__device__ __forceinline__ float mishf(float x) {
  float sp = (x > 20.f) ? x : log1pf(__expf(x));
  return x * tanhf(sp);
}

__device__ __forceinline__ void blockReduce2(float& s, float& ss) {
  #pragma unroll
  for (int off = 32; off > 0; off >>= 1) {
    s  += __shfl_xor(s,  off);
    ss += __shfl_xor(ss, off);
  }
  __shared__ float ls[4], lss[4];
  int w = TID >> 6;
  if ((TID & 63) == 0) { ls[w] = s; lss[w] = ss; }
  __syncthreads();
  s  = ls[0] + ls[1] + ls[2] + ls[3];
  ss = lss[0] + lss[1] + lss[2] + lss[3];
}

// ---------------- GroupNorm(32) fused stats+apply: one block per (b, g) ----------------
__global__ __launch_bounds__(256) void gn1_kernel(const float* __restrict__ x,
    const float* __restrict__ w, const float* __restrict__ bv, float* __restrict__ h) {
  int blk = blockIdx.x, b = blk >> 5, g = blk & 31;
  size_t base = ((size_t)b * Cc + g * 16) * Tt;
  const float* xp = x + base;
  float* hp = h + base;
  float s = 0.f, ss = 0.f;
  for (int i = TID * 4; i < 16 * Tt; i += 1024) {
    float4 v = *reinterpret_cast<const float4*>(xp + i);
    s  += v.x + v.y + v.z + v.w;
    ss += v.x * v.x + v.y * v.y + v.z * v.z + v.w * v.w;
  }
  blockReduce2(s, ss);
  float mean = s * (1.f / 16384.f);
  float rstd = rsqrtf(ss * (1.f / 16384.f) - mean * mean + 1e-5f);
  for (int i = TID * 4; i < 16 * Tt; i += 1024) {
    int c = g * 16 + (i >> 10);
    float sw = w[c] * rstd;
    float sb = bv[c] - mean * sw;
    float4 v = *reinterpret_cast<const float4*>(xp + i);
    v.x = v.x * sw + sb; v.y = v.y * sw + sb; v.z = v.z * sw + sb; v.w = v.w * sw + sb;
    *reinterpret_cast<float4*>(hp + i) = v;
  }
}

// ---------------- conv1d K=2 (pad_lo=0, pad_hi=1): y[b,o,t] = sum_ci w0*h[t] + w1*h[t+1] ----------------
__global__ __launch_bounds__(256) void conv_k2_kernel(const float* __restrict__ h,
    const float* __restrict__ w, const float* __restrict__ bias, float* __restrict__ y) {
  __shared__ float hs[32][130];
  __shared__ float wsld[64][66];
  int t0 = blockIdx.x * 128, o0 = blockIdx.y * 64, b = blockIdx.z;
  const float* hb = h + (size_t)b * Cc * Tt;
  float acc[4][8];
  #pragma unroll
  for (int i = 0; i < 4; ++i)
    #pragma unroll
    for (int j = 0; j < 8; ++j) acc[i][j] = 0.f;
  int tx = TID & 15, ty = TID >> 4;
  for (int cc = 0; cc < Cc; cc += 32) {
    __syncthreads();
    for (int idx = TID; idx < 32 * 129; idx += 256) {
      int ci = idx / 129, tt = idx % 129;
      int t = t0 + tt;
      hs[ci][tt] = (t < Tt) ? hb[(size_t)(cc + ci) * Tt + t] : 0.f;
    }
    for (int idx = TID; idx < 64 * 64; idx += 256) {
      int o = idx >> 6, j = idx & 63;
      wsld[o][j] = w[(size_t)(o0 + o) * (Cc * 2) + cc * 2 + j];
    }
    __syncthreads();
    for (int ci = 0; ci < 32; ++ci) {
      float hv[9];
      #pragma unroll
      for (int j = 0; j < 9; ++j) hv[j] = hs[ci][tx * 8 + j];
      #pragma unroll
      for (int oo = 0; oo < 4; ++oo) {
        float w0 = wsld[ty * 4 + oo][ci * 2 + 0];
        float w1 = wsld[ty * 4 + oo][ci * 2 + 1];
        #pragma unroll
        for (int j = 0; j < 8; ++j)
          acc[oo][j] = fmaf(w0, hv[j], fmaf(w1, hv[j + 1], acc[oo][j]));
      }
    }
  }
  #pragma unroll
  for (int oo = 0; oo < 4; ++oo) {
    int o = o0 + ty * 4 + oo;
    float bo = bias[o];
    #pragma unroll
    for (int j = 0; j < 8; ++j)
      y[((size_t)b * C3 + o) * Tt + t0 + tx * 8 + j] = acc[oo][j] + bo;
  }
}

// ---------------- generic GroupNorm stats: one block per contiguous group of n floats ----------------
__global__ __launch_bounds__(256) void gn_stats_kernel(const float* __restrict__ x,
    float2* __restrict__ stats, int n) {
  const float* p = x + (size_t)blockIdx.x * n;
  float s = 0.f, ss = 0.f;
  for (int i = TID * 4; i < n; i += 1024) {
    float4 v = *reinterpret_cast<const float4*>(p + i);
    s  += v.x + v.y + v.z + v.w;
    ss += v.x * v.x + v.y * v.y + v.z * v.z + v.w * v.w;
  }
  blockReduce2(s, ss);
  if (TID == 0) {
    float mean = s / (float)n;
    float var = ss / (float)n - mean * mean;
    stats[blockIdx.x] = make_float2(mean, rsqrtf(var + 1e-5f));
  }
}

// ---------------- GN(8)+Mish applied elementwise in-place on qkv ----------------
__global__ __launch_bounds__(256) void gn2_apply_kernel(float* __restrict__ qkv,
    const float2* __restrict__ st, const float* __restrict__ w, const float* __restrict__ bv) {
  size_t i = ((size_t)blockIdx.x * 256 + TID) * 4;
  int ch = (int)((i >> 10) % C3);
  int b = (int)(i / ((size_t)C3 * Tt));
  float2 ms = st[b * 8 + ch / 192];
  float sw = w[ch] * ms.y;
  float sb = bv[ch] - ms.x * sw;
  float4 v = *reinterpret_cast<float4*>(qkv + i);
  v.x = mishf(v.x * sw + sb);
  v.y = mishf(v.y * sw + sb);
  v.z = mishf(v.z * sw + sb);
  v.w = mishf(v.w * sw + sb);
  *reinterpret_cast<float4*>(qkv + i) = v;
}

// ---------------- attention: block = (16 q-rows, one head-batch) ----------------
__global__ __launch_bounds__(256) void attn_kernel(const float* __restrict__ qkv,
                                                   float* __restrict__ a) {
  __shared__ float q_s[16][64];
  __shared__ __hip_bfloat16 p_s[16][1024];
  __shared__ float v_s[64][65];
  int t0 = blockIdx.x * 16;
  int hb = blockIdx.y;
  int b = hb >> 3, hd = hb & 7;
  const float* q = qkv + ((size_t)b * C3 + hd * 192) * Tt;
  const float* k = q + 64 * Tt;
  const float* v = q + 128 * Tt;
  for (int idx = TID; idx < 16 * 64; idx += 256) {
    int c = idx & 63, r = idx >> 6;
    q_s[r][c] = q[(size_t)c * Tt + t0 + r];
  }
  __syncthreads();
  int wave = TID >> 6, lane = TID & 63;
  // phase 1: QK^T. wave owns rows wave*4..+3, lanes sweep s.
  float sc[64];
  #pragma unroll
  for (int i = 0; i < 64; ++i) sc[i] = 0.f;
  for (int c = 0; c < 64; ++c) {
    float qv0 = q_s[wave * 4 + 0][c];
    float qv1 = q_s[wave * 4 + 1][c];
    float qv2 = q_s[wave * 4 + 2][c];
    float qv3 = q_s[wave * 4 + 3][c];
    const float* krow = k + (size_t)c * Tt + lane;
    #pragma unroll
    for (int so = 0; so < 16; ++so) {
      float kv = krow[so * 64];
      sc[so * 4 + 0] = fmaf(qv0, kv, sc[so * 4 + 0]);
      sc[so * 4 + 1] = fmaf(qv1, kv, sc[so * 4 + 1]);
      sc[so * 4 + 2] = fmaf(qv2, kv, sc[so * 4 + 2]);
      sc[so * 4 + 3] = fmaf(qv3, kv, sc[so * 4 + 3]);
    }
  }
  // softmax per row (scores scaled by 1/8 = (64^-0.25)^2), fp32
  #pragma unroll
  for (int r = 0; r < 4; ++r) {
    float m = -1e30f;
    #pragma unroll
    for (int so = 0; so < 16; ++so) m = fmaxf(m, sc[so * 4 + r]);
    #pragma unroll
    for (int off = 32; off > 0; off >>= 1) m = fmaxf(m, __shfl_xor(m, off));
    float sum = 0.f;
    #pragma unroll
    for (int so = 0; so < 16; ++so) {
      float e = __expf((sc[so * 4 + r] - m) * 0.125f);
      sc[so * 4 + r] = e;
      sum += e;
    }
    #pragma unroll
    for (int off = 32; off > 0; off >>= 1) sum += __shfl_xor(sum, off);
    float inv = 1.f / sum;
    #pragma unroll
    for (int so = 0; so < 16; ++so)
      p_s[wave * 4 + r][so * 64 + lane] = __float2bfloat16(sc[so * 4 + r] * inv);
  }
  // phase 2: O = P @ V^T. lane -> channel, wave -> row group.
  int c2 = TID & 63, rg = TID >> 6;
  float out[4] = {0.f, 0.f, 0.f, 0.f};
  for (int s0 = 0; s0 < Tt; s0 += 64) {
    __syncthreads();
    for (int idx = TID; idx < 64 * 64; idx += 256) {
      int cc2 = idx >> 6, ss = idx & 63;
      v_s[cc2][ss] = v[(size_t)cc2 * Tt + s0 + ss];
    }
    __syncthreads();
    #pragma unroll 8
    for (int ss = 0; ss < 64; ++ss) {
      float vv = v_s[c2][ss];
      #pragma unroll
      for (int j = 0; j < 4; ++j)
        out[j] = fmaf(__bfloat162float(p_s[rg * 4 + j][s0 + ss]), vv, out[j]);
    }
  }
  #pragma unroll
  for (int j = 0; j < 4; ++j)
    a[((size_t)b * Cc + hd * 64 + c2) * Tt + t0 + rg * 4 + j] = out[j];
}

// ---------------- conv1d K=4 (pad_lo=1, pad_hi=2) ----------------
__global__ __launch_bounds__(256) void conv_k4_kernel(const float* __restrict__ a,
    const float* __restrict__ w, const float* __restrict__ bias, float* __restrict__ y) {
  __shared__ float hs[32][134];
  __shared__ float wsld[64][130];
  int t0 = blockIdx.x * 128, o0 = blockIdx.y * 64, b = blockIdx.z;
  const float* ab = a + (size_t)b * Cc * Tt;
  float acc[4][8];
  #pragma unroll
  for (int i = 0; i < 4; ++i)
    #pragma unroll
    for (int j = 0; j < 8; ++j) acc[i][j] = 0.f;
  int tx = TID & 15, ty = TID >> 4;
  for (int cc = 0; cc < Cc; cc += 32) {
    __syncthreads();
    for (int idx = TID; idx < 32 * 131; idx += 256) {
      int ci = idx / 131, tt = idx % 131;
      int t = t0 + tt - 1;
      hs[ci][tt] = (t >= 0 && t < Tt) ? ab[(size_t)(cc + ci) * Tt + t] : 0.f;
    }
    for (int idx = TID; idx < 64 * 128; idx += 256) {
      int o = idx >> 7, j = idx & 127;
      wsld[o][j] = w[(size_t)(o0 + o) * (Cc * 4) + cc * 4 + j];
    }
    __syncthreads();
    for (int ci = 0; ci < 32; ++ci) {
      float hv[11];
      #pragma unroll
      for (int j = 0; j < 11; ++j) hv[j] = hs[ci][tx * 8 + j];
      #pragma unroll
      for (int oo = 0; oo < 4; ++oo) {
        float w0 = wsld[ty * 4 + oo][ci * 4 + 0];
        float w1 = wsld[ty * 4 + oo][ci * 4 + 1];
        float w2 = wsld[ty * 4 + oo][ci * 4 + 2];
        float w3 = wsld[ty * 4 + oo][ci * 4 + 3];
        #pragma unroll
        for (int j = 0; j < 8; ++j)
          acc[oo][j] += w0 * hv[j] + w1 * hv[j + 1] + w2 * hv[j + 2] + w3 * hv[j + 3];
      }
    }
  }
  #pragma unroll
  for (int oo = 0; oo < 4; ++oo) {
    int o = o0 + ty * 4 + oo;
    float bo = bias[o];
    #pragma unroll
    for (int j = 0; j < 8; ++j)
      y[((size_t)b * Cc + o) * Tt + t0 + tx * 8 + j] = acc[oo][j] + bo;
  }
}

// ---------------- final: out = x + mish(gn(y2)) in-place on d_out ----------------
__global__ __launch_bounds__(256) void final_kernel(const float* __restrict__ x,
    float* __restrict__ y, const float2* __restrict__ st,
    const float* __restrict__ w, const float* __restrict__ bv) {
  size_t i = ((size_t)blockIdx.x * 256 + TID) * 4;
  int ch = (int)((i >> 10) & (Cc - 1));
  int b = (int)(i >> 19);
  float2 ms = st[b * 8 + (ch >> 6)];
  float sw = w[ch] * ms.y;
  float sb = bv[ch] - ms.x * sw;
  float4 v  = *reinterpret_cast<const float4*>(y + i);
  float4 xv = *reinterpret_cast<const float4*>(x + i);
  v.x = xv.x + mishf(v.x * sw + sb);
  v.y = xv.y + mishf(v.y * sw + sb);
  v.z = xv.z + mishf(v.z * sw + sb);
  v.w = xv.w + mishf(v.w * sw + sb);
  *reinterpret_cast<float4*>(y + i) = v;
}

extern "C" void kernel_launch(void* const* d_in, const int* in_sizes, int n_in,
                              void* d_out, int out_size, void* d_ws, size_t ws_size,
                              hipStream_t stream) {
  const float* x     = (const float*)d_in[0];
  const float* gn_w  = (const float*)d_in[1];
  const float* gn_b  = (const float*)d_in[2];
  const float* wqkv  = (const float*)d_in[3];
  const float* bqkv  = (const float*)d_in[4];
  const float* gnq_w = (const float*)d_in[5];
  const float* gnq_b = (const float*)d_in[6];
  const float* wproj = (const float*)d_in[7];
  const float* bproj = (const float*)d_in[8];
  const float* gnp_w = (const float*)d_in[9];
  const float* gnp_b = (const float*)d_in[10];
  float* out = (float*)d_out;

  char* ws = (char*)d_ws;
  float* h   = (float*)ws;                                 // 16 MB (reused as attn out)
  float* qkv = (float*)(ws + (size_t)16 * 1024 * 1024);    // 48 MB
  float2* st2 = (float2*)(ws + (size_t)64 * 1024 * 1024);  // 64 entries
  float2* st3 = st2 + 64;                                  // 64 entries

  dim3 blk(256);
  gn1_kernel<<<256, blk, 0, stream>>>(x, gn_w, gn_b, h);
  conv_k2_kernel<<<dim3(8, 24, 8), blk, 0, stream>>>(h, wqkv, bqkv, qkv);
  gn_stats_kernel<<<64, blk, 0, stream>>>(qkv, st2, 192 * 1024);
  gn2_apply_kernel<<<12288, blk, 0, stream>>>(qkv, st2, gnq_w, gnq_b);
  attn_kernel<<<dim3(64, 64), blk, 0, stream>>>(qkv, h);
  conv_k4_kernel<<<dim3(8, 8, 8), blk, 0, stream>>>(h, wproj, bproj, out);
  gn_stats_kernel<<<64, blk, 0, stream>>>(out, st3, 64 * 1024);
  final_kernel<<<4096, blk, 0, stream>>>(x, out, st3, gnp_w, gnp_b);
}

// Round 2
// 859.540 us; speedup vs baseline: 1.8515x; 1.8515x over previous
//
#include <hip/hip_runtime.h>
#include <hip/hip_bf16.h>
#include <math.h>

#define TID threadIdx.x

constexpr int Cc = 512, Tt = 1024, C3 = 1536;

typedef __attribute__((ext_vector_type(8))) __bf16 bf16x8;
typedef __attribute__((ext_vector_type(4))) float f32x4;

__device__ __forceinline__ void async16(const void* g, void* l) {
  __builtin_amdgcn_global_load_lds(
      (const __attribute__((address_space(1))) unsigned int*)g,
      (__attribute__((address_space(3))) unsigned int*)l, 16, 0, 0);
}

__device__ __forceinline__ float mishf(float x) {
  float sp = (x > 20.f) ? x : log1pf(__expf(x));
  return x * tanhf(sp);
}

__device__ __forceinline__ void blockReduce2(float& s, float& ss) {
  #pragma unroll
  for (int off = 32; off > 0; off >>= 1) {
    s  += __shfl_xor(s,  off);
    ss += __shfl_xor(ss, off);
  }
  __shared__ float ls[4], lss[4];
  int w = TID >> 6;
  if ((TID & 63) == 0) { ls[w] = s; lss[w] = ss; }
  __syncthreads();
  s  = ls[0] + ls[1] + ls[2] + ls[3];
  ss = lss[0] + lss[1] + lss[2] + lss[3];
}

// ---------------- fused GN(32) + im2col(K=2, pad_lo=0) -> bf16 B1t[b][t][k=2ci+j] ----------------
__global__ __launch_bounds__(256) void gn1_im2col(const float* __restrict__ x,
    const float* __restrict__ w, const float* __restrict__ bv,
    __hip_bfloat16* __restrict__ B1t) {
  int blk = blockIdx.x, bb = blk >> 5, g = blk & 31;
  size_t base = ((size_t)bb * Cc + g * 16) * Tt;
  const float* xp = x + base;
  float s = 0.f, ss = 0.f;
  for (int i = TID * 4; i < 16 * Tt; i += 1024) {
    float4 v = *reinterpret_cast<const float4*>(xp + i);
    s  += v.x + v.y + v.z + v.w;
    ss += v.x * v.x + v.y * v.y + v.z * v.z + v.w * v.w;
  }
  blockReduce2(s, ss);
  float mean = s * (1.f / 16384.f);
  float rstd = rsqrtf(ss * (1.f / 16384.f) - mean * mean + 1e-5f);
  int ci_l = TID & 15, tof = TID >> 4;
  int ci = g * 16 + ci_l;
  float sw = w[ci] * rstd;
  float sb = bv[ci] - mean * sw;
  const float* xr = xp + (size_t)ci_l * Tt;
  __hip_bfloat16* op = B1t + (size_t)bb * Tt * 1024 + 2 * ci;
  for (int t = tof; t < Tt; t += 16) {
    float h0 = xr[t] * sw + sb;
    float h1 = (t + 1 < Tt) ? xr[t + 1] * sw + sb : 0.f;
    __hip_bfloat162 pr;
    pr.x = __float2bfloat16(h0);
    pr.y = __float2bfloat16(h1);
    *reinterpret_cast<__hip_bfloat162*>(op + (size_t)t * 1024) = pr;
  }
}

// ---------------- im2col(K=4, pad_lo=1) on attn output -> bf16 B4t[b][t][k=4ci+j] ----------------
__global__ __launch_bounds__(256) void im2col_k4(const float* __restrict__ a,
    __hip_bfloat16* __restrict__ B4t) {
  int bb = blockIdx.x >> 5, cg = blockIdx.x & 31;
  int ci = cg * 16 + (TID & 15);
  const float* ar = a + ((size_t)bb * Cc + ci) * Tt;
  __hip_bfloat16* op = B4t + (size_t)bb * Tt * 2048 + 4 * ci;
  for (int t = TID >> 4; t < Tt; t += 16) {
    float v0 = (t >= 1) ? ar[t - 1] : 0.f;
    float v1 = ar[t];
    float v2 = (t + 1 < Tt) ? ar[t + 1] : 0.f;
    float v3 = (t + 2 < Tt) ? ar[t + 2] : 0.f;
    __hip_bfloat162 p0, p1;
    p0.x = __float2bfloat16(v0); p0.y = __float2bfloat16(v1);
    p1.x = __float2bfloat16(v2); p1.y = __float2bfloat16(v3);
    __hip_bfloat16* q = op + (size_t)t * 2048;
    *reinterpret_cast<__hip_bfloat162*>(q) = p0;
    *reinterpret_cast<__hip_bfloat162*>(q + 2) = p1;
  }
}

// ---------------- f32 -> bf16 cast (weights) ----------------
__global__ __launch_bounds__(256) void cast_bf16(const float* __restrict__ in,
    __hip_bfloat16* __restrict__ out, int n) {
  int i = (blockIdx.x * 256 + TID) * 4;
  if (i >= n) return;
  float4 v = *reinterpret_cast<const float4*>(in + i);
  __hip_bfloat162 p0, p1;
  p0.x = __float2bfloat16(v.x); p0.y = __float2bfloat16(v.y);
  p1.x = __float2bfloat16(v.z); p1.y = __float2bfloat16(v.w);
  *reinterpret_cast<__hip_bfloat162*>(out + i) = p0;
  *reinterpret_cast<__hip_bfloat162*>(out + i + 2) = p1;
}

// ---------------- bf16 MFMA GEMM: C[b][o][t] = sum_k A[o][k] * Bt[b][t][k] + bias[o] ----------------
// Tile: MT x 128 (N). 4 waves. Fragment-ordered LDS: 1KB chunk = one wave ds_read_b128 span.
template<int K, int MT>
__global__ __launch_bounds__(256) void gemm_bt(const __hip_bfloat16* __restrict__ A,
    const __hip_bfloat16* __restrict__ Bt, const float* __restrict__ bias,
    float* __restrict__ C, int M) {
  constexpr int ACH = (MT / 16) * 2;       // A chunks of 1KB
  constexpr int NCH = ACH + 16;            // + B chunks (128 cols)
  constexpr int NF  = (MT == 128) ? 4 : 2; // n-fragments per wave
  __shared__ __align__(16) char lds[NCH * 1024];
  int t0 = blockIdx.x * 128, o0 = blockIdx.y * MT, bz = blockIdx.z;
  int wave = TID >> 6, lane = TID & 63;
  int l4 = lane >> 4, r15 = lane & 15;
  const __hip_bfloat16* Ab = A + (size_t)o0 * K;
  const __hip_bfloat16* Bb = Bt + ((size_t)bz * 1024 + t0) * K;
  int mbase = (MT == 128) ? (wave >> 1) * 4 : 0;
  int nbase = (MT == 128) ? (wave & 1) * 4 : wave * 2;

  f32x4 acc[4][NF];
  f32x4 zz = {0.f, 0.f, 0.f, 0.f};
  #pragma unroll
  for (int m = 0; m < 4; ++m)
    #pragma unroll
    for (int n = 0; n < NF; ++n) acc[m][n] = zz;

  for (int kt = 0; kt < K / 64; ++kt) {
    #pragma unroll
    for (int c = 0; c < NCH / 4; ++c) {
      int ch = c * 4 + wave;
      int cl = (ch < ACH) ? ch : ch - ACH;
      int row = (cl >> 1) * 16 + r15;
      int kof = kt * 64 + (cl & 1) * 32 + l4 * 8;
      const __hip_bfloat16* src = (ch < ACH) ? (Ab + (size_t)row * K + kof)
                                             : (Bb + (size_t)row * K + kof);
      async16(src, lds + ch * 1024 + lane * 16);
    }
    __syncthreads();
    #pragma unroll
    for (int kk = 0; kk < 2; ++kk) {
      bf16x8 af[4], bfr[NF];
      #pragma unroll
      for (int m = 0; m < 4; ++m)
        af[m] = *reinterpret_cast<const bf16x8*>(lds + ((mbase + m) * 2 + kk) * 1024 + lane * 16);
      #pragma unroll
      for (int n = 0; n < NF; ++n)
        bfr[n] = *reinterpret_cast<const bf16x8*>(lds + (ACH + (nbase + n) * 2 + kk) * 1024 + lane * 16);
      #pragma unroll
      for (int m = 0; m < 4; ++m)
        #pragma unroll
        for (int n = 0; n < NF; ++n)
          acc[m][n] = __builtin_amdgcn_mfma_f32_16x16x32_bf16(af[m], bfr[n], acc[m][n], 0, 0, 0);
    }
    __syncthreads();
  }

  #pragma unroll
  for (int m = 0; m < 4; ++m)
    #pragma unroll
    for (int n = 0; n < NF; ++n) {
      int ocol = t0 + (nbase + n) * 16 + r15;
      #pragma unroll
      for (int r = 0; r < 4; ++r) {
        int orow = o0 + (mbase + m) * 16 + l4 * 4 + r;
        C[((size_t)bz * M + orow) * 1024 + ocol] = acc[m][n][r] + bias[orow];
      }
    }
}

// ---------------- generic GroupNorm stats ----------------
__global__ __launch_bounds__(256) void gn_stats_kernel(const float* __restrict__ x,
    float2* __restrict__ stats, int n) {
  const float* p = x + (size_t)blockIdx.x * n;
  float s = 0.f, ss = 0.f;
  for (int i = TID * 4; i < n; i += 1024) {
    float4 v = *reinterpret_cast<const float4*>(p + i);
    s  += v.x + v.y + v.z + v.w;
    ss += v.x * v.x + v.y * v.y + v.z * v.z + v.w * v.w;
  }
  blockReduce2(s, ss);
  if (TID == 0) {
    float mean = s / (float)n;
    float var = ss / (float)n - mean * mean;
    stats[blockIdx.x] = make_float2(mean, rsqrtf(var + 1e-5f));
  }
}

// ---------------- GN(8)+Mish applied elementwise in-place on qkv ----------------
__global__ __launch_bounds__(256) void gn2_apply_kernel(float* __restrict__ qkv,
    const float2* __restrict__ st, const float* __restrict__ w, const float* __restrict__ bv) {
  size_t i = ((size_t)blockIdx.x * 256 + TID) * 4;
  int ch = (int)((i >> 10) % C3);
  int b = (int)(i / ((size_t)C3 * Tt));
  float2 ms = st[b * 8 + ch / 192];
  float sw = w[ch] * ms.y;
  float sb = bv[ch] - ms.x * sw;
  float4 v = *reinterpret_cast<float4*>(qkv + i);
  v.x = mishf(v.x * sw + sb);
  v.y = mishf(v.y * sw + sb);
  v.z = mishf(v.z * sw + sb);
  v.w = mishf(v.w * sw + sb);
  *reinterpret_cast<float4*>(qkv + i) = v;
}

// ---------------- attention: block = (16 q-rows, one head-batch) ----------------
__global__ __launch_bounds__(256) void attn_kernel(const float* __restrict__ qkv,
                                                   float* __restrict__ a) {
  __shared__ float q_s[16][64];
  __shared__ __hip_bfloat16 p_s[16][1024];
  __shared__ float v_s[64][65];
  int t0 = blockIdx.x * 16;
  int hb = blockIdx.y;
  int b = hb >> 3, hd = hb & 7;
  const float* q = qkv + ((size_t)b * C3 + hd * 192) * Tt;
  const float* k = q + 64 * Tt;
  const float* v = q + 128 * Tt;
  for (int idx = TID; idx < 16 * 64; idx += 256) {
    int c = idx & 63, r = idx >> 6;
    q_s[r][c] = q[(size_t)c * Tt + t0 + r];
  }
  __syncthreads();
  int wave = TID >> 6, lane = TID & 63;
  float sc[64];
  #pragma unroll
  for (int i = 0; i < 64; ++i) sc[i] = 0.f;
  for (int c = 0; c < 64; ++c) {
    float qv0 = q_s[wave * 4 + 0][c];
    float qv1 = q_s[wave * 4 + 1][c];
    float qv2 = q_s[wave * 4 + 2][c];
    float qv3 = q_s[wave * 4 + 3][c];
    const float* krow = k + (size_t)c * Tt + lane;
    #pragma unroll
    for (int so = 0; so < 16; ++so) {
      float kv = krow[so * 64];
      sc[so * 4 + 0] = fmaf(qv0, kv, sc[so * 4 + 0]);
      sc[so * 4 + 1] = fmaf(qv1, kv, sc[so * 4 + 1]);
      sc[so * 4 + 2] = fmaf(qv2, kv, sc[so * 4 + 2]);
      sc[so * 4 + 3] = fmaf(qv3, kv, sc[so * 4 + 3]);
    }
  }
  #pragma unroll
  for (int r = 0; r < 4; ++r) {
    float m = -1e30f;
    #pragma unroll
    for (int so = 0; so < 16; ++so) m = fmaxf(m, sc[so * 4 + r]);
    #pragma unroll
    for (int off = 32; off > 0; off >>= 1) m = fmaxf(m, __shfl_xor(m, off));
    float sum = 0.f;
    #pragma unroll
    for (int so = 0; so < 16; ++so) {
      float e = __expf((sc[so * 4 + r] - m) * 0.125f);
      sc[so * 4 + r] = e;
      sum += e;
    }
    #pragma unroll
    for (int off = 32; off > 0; off >>= 1) sum += __shfl_xor(sum, off);
    float inv = 1.f / sum;
    #pragma unroll
    for (int so = 0; so < 16; ++so)
      p_s[wave * 4 + r][so * 64 + lane] = __float2bfloat16(sc[so * 4 + r] * inv);
  }
  int c2 = TID & 63, rg = TID >> 6;
  float out[4] = {0.f, 0.f, 0.f, 0.f};
  for (int s0 = 0; s0 < Tt; s0 += 64) {
    __syncthreads();
    for (int idx = TID; idx < 64 * 64; idx += 256) {
      int cc2 = idx >> 6, ssx = idx & 63;
      v_s[cc2][ssx] = v[(size_t)cc2 * Tt + s0 + ssx];
    }
    __syncthreads();
    #pragma unroll 8
    for (int ssx = 0; ssx < 64; ++ssx) {
      float vv = v_s[c2][ssx];
      #pragma unroll
      for (int j = 0; j < 4; ++j)
        out[j] = fmaf(__bfloat162float(p_s[rg * 4 + j][s0 + ssx]), vv, out[j]);
    }
  }
  #pragma unroll
  for (int j = 0; j < 4; ++j)
    a[((size_t)b * Cc + hd * 64 + c2) * Tt + t0 + rg * 4 + j] = out[j];
}

// ---------------- final: out = x + mish(gn(y2)) in-place on d_out ----------------
__global__ __launch_bounds__(256) void final_kernel(const float* __restrict__ x,
    float* __restrict__ y, const float2* __restrict__ st,
    const float* __restrict__ w, const float* __restrict__ bv) {
  size_t i = ((size_t)blockIdx.x * 256 + TID) * 4;
  int ch = (int)((i >> 10) & (Cc - 1));
  int b = (int)(i >> 19);
  float2 ms = st[b * 8 + (ch >> 6)];
  float sw = w[ch] * ms.y;
  float sb = bv[ch] - ms.x * sw;
  float4 v  = *reinterpret_cast<const float4*>(y + i);
  float4 xv = *reinterpret_cast<const float4*>(x + i);
  v.x = xv.x + mishf(v.x * sw + sb);
  v.y = xv.y + mishf(v.y * sw + sb);
  v.z = xv.z + mishf(v.z * sw + sb);
  v.w = xv.w + mishf(v.w * sw + sb);
  *reinterpret_cast<float4*>(y + i) = v;
}

extern "C" void kernel_launch(void* const* d_in, const int* in_sizes, int n_in,
                              void* d_out, int out_size, void* d_ws, size_t ws_size,
                              hipStream_t stream) {
  const float* x     = (const float*)d_in[0];
  const float* gn_w  = (const float*)d_in[1];
  const float* gn_b  = (const float*)d_in[2];
  const float* wqkv  = (const float*)d_in[3];
  const float* bqkv  = (const float*)d_in[4];
  const float* gnq_w = (const float*)d_in[5];
  const float* gnq_b = (const float*)d_in[6];
  const float* wproj = (const float*)d_in[7];
  const float* bproj = (const float*)d_in[8];
  const float* gnp_w = (const float*)d_in[9];
  const float* gnp_b = (const float*)d_in[10];
  float* out = (float*)d_out;

  char* ws = (char*)d_ws;
  const size_t MB = 1024 * 1024;
  // Time-multiplexed workspace (64MB + 1KB, same footprint as the passing round-0):
  float* qkv = (float*)ws;                                   // [0,48MB) f32, dead after attn
  __hip_bfloat16* B4t = (__hip_bfloat16*)ws;                 // [0,32MB) bf16, after attn
  __hip_bfloat16* A2  = (__hip_bfloat16*)(ws + 36 * MB);     // [36,38MB), after attn
  __hip_bfloat16* A1  = (__hip_bfloat16*)(ws + 48 * MB);     // [48,51MB), dead after gemm1
  float* hbuf = (float*)(ws + 48 * MB);                      // [48,64MB) attn out (overwrites A1)
  float2* st2 = (float2*)(ws + 64 * MB);
  float2* st3 = st2 + 64;
  __hip_bfloat16* B1t = (__hip_bfloat16*)d_out;              // d_out doubles as B1t (16MB), then
                                                             // gemm2 fully overwrites it.
  dim3 blk(256);
  cast_bf16<<<1536, blk, 0, stream>>>(wqkv, A1, C3 * 1024);
  gn1_im2col<<<256, blk, 0, stream>>>(x, gn_w, gn_b, B1t);
  gemm_bt<1024, 128><<<dim3(8, 12, 8), blk, 0, stream>>>(A1, B1t, bqkv, qkv, C3);
  gn_stats_kernel<<<64, blk, 0, stream>>>(qkv, st2, 192 * 1024);
  gn2_apply_kernel<<<12288, blk, 0, stream>>>(qkv, st2, gnq_w, gnq_b);
  attn_kernel<<<dim3(64, 64), blk, 0, stream>>>(qkv, hbuf);
  im2col_k4<<<256, blk, 0, stream>>>(hbuf, B4t);
  cast_bf16<<<1024, blk, 0, stream>>>(wproj, A2, Cc * 2048);
  gemm_bt<2048, 64><<<dim3(8, 8, 8), blk, 0, stream>>>(A2, B4t, bproj, out, Cc);
  gn_stats_kernel<<<64, blk, 0, stream>>>(out, st3, 64 * 1024);
  final_kernel<<<4096, blk, 0, stream>>>(x, out, st3, gnp_w, gnp_b);
}

// Round 3
// 406.622 us; speedup vs baseline: 3.9139x; 2.1139x over previous
//
#include <hip/hip_runtime.h>
#include <hip/hip_bf16.h>
#include <math.h>

#define TID threadIdx.x

constexpr int Cc = 512, Tt = 1024, C3 = 1536;

typedef __attribute__((ext_vector_type(8))) __bf16 bf16x8;
typedef __attribute__((ext_vector_type(4))) float f32x4;

__device__ __forceinline__ void async16(const void* g, void* l) {
  __builtin_amdgcn_global_load_lds(
      (const __attribute__((address_space(1))) unsigned int*)g,
      (__attribute__((address_space(3))) unsigned int*)l, 16, 0, 0);
}

__device__ __forceinline__ unsigned int pack2bf(float a, float b) {
  __hip_bfloat162 h;
  h.x = __float2bfloat16(a);
  h.y = __float2bfloat16(b);
  return *reinterpret_cast<unsigned int*>(&h);
}

__device__ __forceinline__ float mishf(float x) {
  float sp = (x > 20.f) ? x : log1pf(__expf(x));
  return x * tanhf(sp);
}

__device__ __forceinline__ void blockReduce2(float& s, float& ss) {
  #pragma unroll
  for (int off = 32; off > 0; off >>= 1) {
    s  += __shfl_xor(s,  off);
    ss += __shfl_xor(ss, off);
  }
  __shared__ float ls[4], lss[4];
  int w = TID >> 6;
  if ((TID & 63) == 0) { ls[w] = s; lss[w] = ss; }
  __syncthreads();
  s  = ls[0] + ls[1] + ls[2] + ls[3];
  ss = lss[0] + lss[1] + lss[2] + lss[3];
}

// ---------------- fused GN(32) + im2col(K=2, pad_lo=0) -> bf16 B1t[b][t][k=2ci+j] ----------------
__global__ __launch_bounds__(256) void gn1_im2col(const float* __restrict__ x,
    const float* __restrict__ w, const float* __restrict__ bv,
    __hip_bfloat16* __restrict__ B1t) {
  int blk = blockIdx.x, bb = blk >> 5, g = blk & 31;
  size_t base = ((size_t)bb * Cc + g * 16) * Tt;
  const float* xp = x + base;
  float s = 0.f, ss = 0.f;
  for (int i = TID * 4; i < 16 * Tt; i += 1024) {
    float4 v = *reinterpret_cast<const float4*>(xp + i);
    s  += v.x + v.y + v.z + v.w;
    ss += v.x * v.x + v.y * v.y + v.z * v.z + v.w * v.w;
  }
  blockReduce2(s, ss);
  float mean = s * (1.f / 16384.f);
  float rstd = rsqrtf(ss * (1.f / 16384.f) - mean * mean + 1e-5f);
  int ci_l = TID & 15, tof = TID >> 4;
  int ci = g * 16 + ci_l;
  float sw = w[ci] * rstd;
  float sb = bv[ci] - mean * sw;
  const float* xr = xp + (size_t)ci_l * Tt;
  __hip_bfloat16* op = B1t + (size_t)bb * Tt * 1024 + 2 * ci;
  for (int t = tof; t < Tt; t += 16) {
    float h0 = xr[t] * sw + sb;
    float h1 = (t + 1 < Tt) ? xr[t + 1] * sw + sb : 0.f;
    __hip_bfloat162 pr;
    pr.x = __float2bfloat16(h0);
    pr.y = __float2bfloat16(h1);
    *reinterpret_cast<__hip_bfloat162*>(op + (size_t)t * 1024) = pr;
  }
}

// ---------------- im2col(K=4, pad_lo=1) on attn output -> bf16 B4t[b][t][k=4ci+j] ----------------
__global__ __launch_bounds__(256) void im2col_k4(const float* __restrict__ a,
    __hip_bfloat16* __restrict__ B4t) {
  int bb = blockIdx.x >> 5, cg = blockIdx.x & 31;
  int ci = cg * 16 + (TID & 15);
  const float* ar = a + ((size_t)bb * Cc + ci) * Tt;
  __hip_bfloat16* op = B4t + (size_t)bb * Tt * 2048 + 4 * ci;
  for (int t = TID >> 4; t < Tt; t += 16) {
    float v0 = (t >= 1) ? ar[t - 1] : 0.f;
    float v1 = ar[t];
    float v2 = (t + 1 < Tt) ? ar[t + 1] : 0.f;
    float v3 = (t + 2 < Tt) ? ar[t + 2] : 0.f;
    __hip_bfloat162 p0, p1;
    p0.x = __float2bfloat16(v0); p0.y = __float2bfloat16(v1);
    p1.x = __float2bfloat16(v2); p1.y = __float2bfloat16(v3);
    __hip_bfloat16* q = op + (size_t)t * 2048;
    *reinterpret_cast<__hip_bfloat162*>(q) = p0;
    *reinterpret_cast<__hip_bfloat162*>(q + 2) = p1;
  }
}

// ---------------- f32 -> bf16 cast (weights) ----------------
__global__ __launch_bounds__(256) void cast_bf16(const float* __restrict__ in,
    __hip_bfloat16* __restrict__ out, int n) {
  int i = (blockIdx.x * 256 + TID) * 4;
  if (i >= n) return;
  float4 v = *reinterpret_cast<const float4*>(in + i);
  __hip_bfloat162 p0, p1;
  p0.x = __float2bfloat16(v.x); p0.y = __float2bfloat16(v.y);
  p1.x = __float2bfloat16(v.z); p1.y = __float2bfloat16(v.w);
  *reinterpret_cast<__hip_bfloat162*>(out + i) = p0;
  *reinterpret_cast<__hip_bfloat162*>(out + i + 2) = p1;
}

// ---------------- bf16 MFMA GEMM: C[b][o][t] = sum_k A[o][k] * Bt[b][t][k] + bias[o] ----------------
template<int K, int MT>
__global__ __launch_bounds__(256) void gemm_bt(const __hip_bfloat16* __restrict__ A,
    const __hip_bfloat16* __restrict__ Bt, const float* __restrict__ bias,
    float* __restrict__ C, int M) {
  constexpr int ACH = (MT / 16) * 2;
  constexpr int NCH = ACH + 16;
  constexpr int NF  = (MT == 128) ? 4 : 2;
  __shared__ __align__(16) char lds[NCH * 1024];
  int t0 = blockIdx.x * 128, o0 = blockIdx.y * MT, bz = blockIdx.z;
  int wave = TID >> 6, lane = TID & 63;
  int l4 = lane >> 4, r15 = lane & 15;
  const __hip_bfloat16* Ab = A + (size_t)o0 * K;
  const __hip_bfloat16* Bb = Bt + ((size_t)bz * 1024 + t0) * K;
  int mbase = (MT == 128) ? (wave >> 1) * 4 : 0;
  int nbase = (MT == 128) ? (wave & 1) * 4 : wave * 2;

  f32x4 acc[4][NF];
  f32x4 zz = {0.f, 0.f, 0.f, 0.f};
  #pragma unroll
  for (int m = 0; m < 4; ++m)
    #pragma unroll
    for (int n = 0; n < NF; ++n) acc[m][n] = zz;

  for (int kt = 0; kt < K / 64; ++kt) {
    #pragma unroll
    for (int c = 0; c < NCH / 4; ++c) {
      int ch = c * 4 + wave;
      int cl = (ch < ACH) ? ch : ch - ACH;
      int row = (cl >> 1) * 16 + r15;
      int kof = kt * 64 + (cl & 1) * 32 + l4 * 8;
      const __hip_bfloat16* src = (ch < ACH) ? (Ab + (size_t)row * K + kof)
                                             : (Bb + (size_t)row * K + kof);
      async16(src, lds + ch * 1024 + lane * 16);
    }
    __syncthreads();
    #pragma unroll
    for (int kk = 0; kk < 2; ++kk) {
      bf16x8 af[4], bfr[NF];
      #pragma unroll
      for (int m = 0; m < 4; ++m)
        af[m] = *reinterpret_cast<const bf16x8*>(lds + ((mbase + m) * 2 + kk) * 1024 + lane * 16);
      #pragma unroll
      for (int n = 0; n < NF; ++n)
        bfr[n] = *reinterpret_cast<const bf16x8*>(lds + (ACH + (nbase + n) * 2 + kk) * 1024 + lane * 16);
      #pragma unroll
      for (int m = 0; m < 4; ++m)
        #pragma unroll
        for (int n = 0; n < NF; ++n)
          acc[m][n] = __builtin_amdgcn_mfma_f32_16x16x32_bf16(af[m], bfr[n], acc[m][n], 0, 0, 0);
    }
    __syncthreads();
  }

  #pragma unroll
  for (int m = 0; m < 4; ++m)
    #pragma unroll
    for (int n = 0; n < NF; ++n) {
      int ocol = t0 + (nbase + n) * 16 + r15;
      #pragma unroll
      for (int r = 0; r < 4; ++r) {
        int orow = o0 + (mbase + m) * 16 + l4 * 4 + r;
        C[((size_t)bz * M + orow) * 1024 + ocol] = acc[m][n][r] + bias[orow];
      }
    }
}

// ---------------- generic GroupNorm stats ----------------
__global__ __launch_bounds__(256) void gn_stats_kernel(const float* __restrict__ x,
    float2* __restrict__ stats, int n) {
  const float* p = x + (size_t)blockIdx.x * n;
  float s = 0.f, ss = 0.f;
  for (int i = TID * 4; i < n; i += 1024) {
    float4 v = *reinterpret_cast<const float4*>(p + i);
    s  += v.x + v.y + v.z + v.w;
    ss += v.x * v.x + v.y * v.y + v.z * v.z + v.w * v.w;
  }
  blockReduce2(s, ss);
  if (TID == 0) {
    float mean = s / (float)n;
    float var = ss / (float)n - mean * mean;
    stats[blockIdx.x] = make_float2(mean, rsqrtf(var + 1e-5f));
  }
}

// ---------------- GN(8)+Mish applied elementwise in-place on qkv ----------------
__global__ __launch_bounds__(256) void gn2_apply_kernel(float* __restrict__ qkv,
    const float2* __restrict__ st, const float* __restrict__ w, const float* __restrict__ bv) {
  size_t i = ((size_t)blockIdx.x * 256 + TID) * 4;
  int ch = (int)((i >> 10) % C3);
  int b = (int)(i / ((size_t)C3 * Tt));
  float2 ms = st[b * 8 + ch / 192];
  float sw = w[ch] * ms.y;
  float sb = bv[ch] - ms.x * sw;
  float4 v = *reinterpret_cast<float4*>(qkv + i);
  v.x = mishf(v.x * sw + sb);
  v.y = mishf(v.y * sw + sb);
  v.z = mishf(v.z * sw + sb);
  v.w = mishf(v.w * sw + sb);
  *reinterpret_cast<float4*>(qkv + i) = v;
}

// ---------------- MFMA flash attention ----------------
// block = 4 waves, 64 q-rows of one head-batch. grid = (16 q-tiles, 64 hb).
// LDS (32KB): qt[64t][64c]bf16 | kt[64s][64c]bf16 | v[64c][64s]bf16 | p[4][16t][64s]bf16
//             o[64c][64t]f32 aliases kt+v after the s-loop.
// All tiles use 16B-chunk XOR swizzle: chunk' = chunk ^ (row&7)  -> 2-way (free) ds_read_b128.
__global__ __launch_bounds__(256) void attn_mfma(const float* __restrict__ qkv,
                                                 float* __restrict__ a) {
  __shared__ __align__(16) char smem[32768];
  char* qt = smem;
  char* kt = smem + 8192;
  char* vv = smem + 16384;
  char* pp = smem + 24576;
  char* ov = smem + 8192;   // 16KB alias over kt+vv

  int t0 = blockIdx.x * 64;
  int hb = blockIdx.y, b = hb >> 3, hd = hb & 7;
  const float* Qp = qkv + ((size_t)b * C3 + hd * 192) * Tt;
  const float* Kp = Qp + 64 * Tt;
  const float* Vp = Qp + 128 * Tt;
  int lane = TID & 63, wave = TID >> 6;
  int l4 = lane >> 4, r15 = lane & 15;

  // stage Q^T (bf16, transposed, swizzled): qt[t][c]
  for (int u = TID; u < 512; u += 256) {
    int cp = u >> 4, tq = u & 15;
    int c = cp * 2, t4 = tq * 4;
    const float* q0 = Qp + (size_t)c * Tt + t0 + t4;
    float4 qa = *reinterpret_cast<const float4*>(q0);
    float4 qb = *reinterpret_cast<const float4*>(q0 + Tt);
    float ax[4] = {qa.x, qa.y, qa.z, qa.w}, bx[4] = {qb.x, qb.y, qb.z, qb.w};
    #pragma unroll
    for (int i = 0; i < 4; ++i) {
      int t = t4 + i;
      *reinterpret_cast<unsigned int*>(qt + t * 128 + ((((c >> 3) ^ (t & 7)) << 4) | ((c & 7) * 2)))
          = pack2bf(ax[i], bx[i]);
    }
  }

  f32x4 osum[4];
  f32x4 zz = {0.f, 0.f, 0.f, 0.f};
  #pragma unroll
  for (int cf = 0; cf < 4; ++cf) osum[cf] = zz;
  float mrow[4] = {-1e30f, -1e30f, -1e30f, -1e30f};
  float lrow[4] = {0.f, 0.f, 0.f, 0.f};
  __syncthreads();

  for (int s0 = 0; s0 < Tt; s0 += 64) {
    __syncthreads();  // prior iteration's LDS reads complete
    // stage K^T: kt[s][c]
    for (int u = TID; u < 512; u += 256) {
      int cp = u >> 4, sq = u & 15;
      int c = cp * 2, s4 = sq * 4;
      const float* k0 = Kp + (size_t)c * Tt + s0 + s4;
      float4 ka = *reinterpret_cast<const float4*>(k0);
      float4 kb = *reinterpret_cast<const float4*>(k0 + Tt);
      float ax[4] = {ka.x, ka.y, ka.z, ka.w}, bx[4] = {kb.x, kb.y, kb.z, kb.w};
      #pragma unroll
      for (int i = 0; i < 4; ++i) {
        int s = s4 + i;
        *reinterpret_cast<unsigned int*>(kt + s * 128 + ((((c >> 3) ^ (s & 7)) << 4) | ((c & 7) * 2)))
            = pack2bf(ax[i], bx[i]);
      }
    }
    // stage V: vv[c][s]
    for (int u = TID; u < 1024; u += 256) {
      int c = u >> 4, sq = u & 15;
      int s = sq * 4;
      float4 v4 = *reinterpret_cast<const float4*>(Vp + (size_t)c * Tt + s0 + s);
      char* base = vv + c * 128 + (((s >> 3) ^ (c & 7)) << 4) + (s & 7) * 2;
      *reinterpret_cast<unsigned int*>(base)     = pack2bf(v4.x, v4.y);
      *reinterpret_cast<unsigned int*>(base + 4) = pack2bf(v4.z, v4.w);
    }
    __syncthreads();

    // QK^T: per wave 16t x 64s
    bf16x8 aq[2];
    int tg = wave * 16 + r15;
    #pragma unroll
    for (int kk = 0; kk < 2; ++kk)
      aq[kk] = *reinterpret_cast<const bf16x8*>(qt + tg * 128 + (((kk * 4 + l4) ^ (tg & 7)) << 4));
    f32x4 sc[4];
    #pragma unroll
    for (int sf = 0; sf < 4; ++sf) sc[sf] = zz;
    #pragma unroll
    for (int sf = 0; sf < 4; ++sf) {
      int sr = sf * 16 + r15;
      #pragma unroll
      for (int kk = 0; kk < 2; ++kk) {
        bf16x8 bk = *reinterpret_cast<const bf16x8*>(kt + sr * 128 + (((kk * 4 + l4) ^ (sr & 7)) << 4));
        sc[sf] = __builtin_amdgcn_mfma_f32_16x16x32_bf16(aq[kk], bk, sc[sf], 0, 0, 0);
      }
    }

    // online softmax (scores scaled by 0.125 inside exp); rows = l4*4+r
    float tmax[4];
    #pragma unroll
    for (int r = 0; r < 4; ++r)
      tmax[r] = fmaxf(fmaxf(sc[0][r], sc[1][r]), fmaxf(sc[2][r], sc[3][r]));
    #pragma unroll
    for (int off = 1; off < 16; off <<= 1)
      #pragma unroll
      for (int r = 0; r < 4; ++r) tmax[r] = fmaxf(tmax[r], __shfl_xor(tmax[r], off));
    float alpha[4];
    #pragma unroll
    for (int r = 0; r < 4; ++r) {
      float mnew = fmaxf(mrow[r], tmax[r]);
      alpha[r] = __expf((mrow[r] - mnew) * 0.125f);
      mrow[r] = mnew;
      lrow[r] *= alpha[r];
    }
    #pragma unroll
    for (int cf = 0; cf < 4; ++cf)
      #pragma unroll
      for (int r = 0; r < 4; ++r) osum[cf][r] *= alpha[r];
    // P = exp((s-m)/8), write bf16 to wave-local p tile [16t][64s]
    char* pw = pp + wave * 2048;
    float psum[4] = {0.f, 0.f, 0.f, 0.f};
    #pragma unroll
    for (int sf = 0; sf < 4; ++sf) {
      int s = sf * 16 + r15;
      int chunkbase = (s >> 3) << 0;
      #pragma unroll
      for (int r = 0; r < 4; ++r) {
        float p = __expf((sc[sf][r] - mrow[r]) * 0.125f);
        psum[r] += p;
        int tl = l4 * 4 + r;
        *reinterpret_cast<__hip_bfloat16*>(pw + tl * 128 + ((((s >> 3) ^ (tl & 7)) << 4) | ((s & 7) * 2)))
            = __float2bfloat16(p);
      }
      (void)chunkbase;
    }
    #pragma unroll
    for (int r = 0; r < 4; ++r) lrow[r] += psum[r];
    asm volatile("s_waitcnt lgkmcnt(0)" ::: "memory");

    // PV: O[16t][64c] += P(16t x 64s) * V^T(64s x 64c)
    bf16x8 pa[2];
    #pragma unroll
    for (int kk = 0; kk < 2; ++kk)
      pa[kk] = *reinterpret_cast<const bf16x8*>(pw + r15 * 128 + (((kk * 4 + l4) ^ (r15 & 7)) << 4));
    #pragma unroll
    for (int cf = 0; cf < 4; ++cf) {
      int cr = cf * 16 + r15;
      #pragma unroll
      for (int kk = 0; kk < 2; ++kk) {
        bf16x8 bv = *reinterpret_cast<const bf16x8*>(vv + cr * 128 + (((kk * 4 + l4) ^ (cr & 7)) << 4));
        osum[cf] = __builtin_amdgcn_mfma_f32_16x16x32_bf16(pa[kk], bv, osum[cf], 0, 0, 0);
      }
    }
  }

  // reduce l across the 16-lane row group
  #pragma unroll
  for (int off = 1; off < 16; off <<= 1)
    #pragma unroll
    for (int r = 0; r < 4; ++r) lrow[r] += __shfl_xor(lrow[r], off);
  float linv[4];
  #pragma unroll
  for (int r = 0; r < 4; ++r) linv[r] = 1.f / lrow[r];

  __syncthreads();  // all PV reads done; safe to overwrite kt/vv with o
  // write O to ov[c][t] f32 (chunk-swizzled), then coalesced global store
  #pragma unroll
  for (int cf = 0; cf < 4; ++cf) {
    int c = cf * 16 + r15;
    #pragma unroll
    for (int r = 0; r < 4; ++r) {
      int t = wave * 16 + l4 * 4 + r;
      *reinterpret_cast<float*>(ov + c * 256 + ((((t >> 2) ^ (c & 7)) << 4) | ((t & 3) * 4)))
          = osum[cf][r] * linv[r];
    }
  }
  __syncthreads();
  float* ap = a + ((size_t)b * Cc + hd * 64) * Tt + t0;
  for (int u = TID; u < 1024; u += 256) {
    int c = u >> 4, tq = u & 15;
    float4 o4 = *reinterpret_cast<const float4*>(ov + c * 256 + (((tq ^ (c & 7)) << 4)));
    *reinterpret_cast<float4*>(ap + (size_t)c * Tt + tq * 4) = o4;
  }
}

// ---------------- final: out = x + mish(gn(y2)) in-place on d_out ----------------
__global__ __launch_bounds__(256) void final_kernel(const float* __restrict__ x,
    float* __restrict__ y, const float2* __restrict__ st,
    const float* __restrict__ w, const float* __restrict__ bv) {
  size_t i = ((size_t)blockIdx.x * 256 + TID) * 4;
  int ch = (int)((i >> 10) & (Cc - 1));
  int b = (int)(i >> 19);
  float2 ms = st[b * 8 + (ch >> 6)];
  float sw = w[ch] * ms.y;
  float sb = bv[ch] - ms.x * sw;
  float4 v  = *reinterpret_cast<const float4*>(y + i);
  float4 xv = *reinterpret_cast<const float4*>(x + i);
  v.x = xv.x + mishf(v.x * sw + sb);
  v.y = xv.y + mishf(v.y * sw + sb);
  v.z = xv.z + mishf(v.z * sw + sb);
  v.w = xv.w + mishf(v.w * sw + sb);
  *reinterpret_cast<float4*>(y + i) = v;
}

extern "C" void kernel_launch(void* const* d_in, const int* in_sizes, int n_in,
                              void* d_out, int out_size, void* d_ws, size_t ws_size,
                              hipStream_t stream) {
  const float* x     = (const float*)d_in[0];
  const float* gn_w  = (const float*)d_in[1];
  const float* gn_b  = (const float*)d_in[2];
  const float* wqkv  = (const float*)d_in[3];
  const float* bqkv  = (const float*)d_in[4];
  const float* gnq_w = (const float*)d_in[5];
  const float* gnq_b = (const float*)d_in[6];
  const float* wproj = (const float*)d_in[7];
  const float* bproj = (const float*)d_in[8];
  const float* gnp_w = (const float*)d_in[9];
  const float* gnp_b = (const float*)d_in[10];
  float* out = (float*)d_out;

  char* ws = (char*)d_ws;
  const size_t MB = 1024 * 1024;
  float* qkv = (float*)ws;                                   // [0,48MB) f32, dead after attn
  __hip_bfloat16* B4t = (__hip_bfloat16*)ws;                 // [0,32MB) bf16, after attn
  __hip_bfloat16* A2  = (__hip_bfloat16*)(ws + 36 * MB);     // [36,38MB)
  __hip_bfloat16* A1  = (__hip_bfloat16*)(ws + 48 * MB);     // [48,51MB), dead after gemm1
  float* hbuf = (float*)(ws + 48 * MB);                      // [48,64MB) attn out
  float2* st2 = (float2*)(ws + 64 * MB);
  float2* st3 = st2 + 64;
  __hip_bfloat16* B1t = (__hip_bfloat16*)d_out;              // d_out doubles as B1t

  dim3 blk(256);
  cast_bf16<<<1536, blk, 0, stream>>>(wqkv, A1, C3 * 1024);
  gn1_im2col<<<256, blk, 0, stream>>>(x, gn_w, gn_b, B1t);
  gemm_bt<1024, 128><<<dim3(8, 12, 8), blk, 0, stream>>>(A1, B1t, bqkv, qkv, C3);
  gn_stats_kernel<<<64, blk, 0, stream>>>(qkv, st2, 192 * 1024);
  gn2_apply_kernel<<<12288, blk, 0, stream>>>(qkv, st2, gnq_w, gnq_b);
  attn_mfma<<<dim3(16, 64), blk, 0, stream>>>(qkv, hbuf);
  im2col_k4<<<256, blk, 0, stream>>>(hbuf, B4t);
  cast_bf16<<<1024, blk, 0, stream>>>(wproj, A2, Cc * 2048);
  gemm_bt<2048, 64><<<dim3(8, 8, 8), blk, 0, stream>>>(A2, B4t, bproj, out, Cc);
  gn_stats_kernel<<<64, blk, 0, stream>>>(out, st3, 64 * 1024);
  final_kernel<<<4096, blk, 0, stream>>>(x, out, st3, gnp_w, gnp_b);
}

// Round 4
// 346.034 us; speedup vs baseline: 4.5992x; 1.1751x over previous
//
#include <hip/hip_runtime.h>
#include <hip/hip_bf16.h>
#include <math.h>

#define TID threadIdx.x

constexpr int Cc = 512, Tt = 1024, C3 = 1536;

typedef __attribute__((ext_vector_type(8))) __bf16 bf16x8;
typedef __attribute__((ext_vector_type(4))) float f32x4;

__device__ __forceinline__ void async16(const void* g, void* l) {
  __builtin_amdgcn_global_load_lds(
      (const __attribute__((address_space(1))) unsigned int*)g,
      (__attribute__((address_space(3))) unsigned int*)l, 16, 0, 0);
}

__device__ __forceinline__ unsigned int pack2bf(float a, float b) {
  __hip_bfloat162 h;
  h.x = __float2bfloat16(a);
  h.y = __float2bfloat16(b);
  return *reinterpret_cast<unsigned int*>(&h);
}

__device__ __forceinline__ float mishf(float x) {
  float sp = (x > 20.f) ? x : log1pf(__expf(x));
  return x * tanhf(sp);
}

__device__ __forceinline__ void blockReduce2(float& s, float& ss) {
  #pragma unroll
  for (int off = 32; off > 0; off >>= 1) {
    s  += __shfl_xor(s,  off);
    ss += __shfl_xor(ss, off);
  }
  __shared__ float ls[4], lss[4];
  int w = TID >> 6;
  if ((TID & 63) == 0) { ls[w] = s; lss[w] = ss; }
  __syncthreads();
  s  = ls[0] + ls[1] + ls[2] + ls[3];
  ss = lss[0] + lss[1] + lss[2] + lss[3];
}

// ---------------- fused GN(32) + im2col(K=2, pad_lo=0) -> bf16 B1t[b][t][k=2ci+j] ----------------
// Coalesced: normalize into LDS, pack 16B chunks, dwordx4 stores.
__global__ __launch_bounds__(256) void gn1_im2col(const float* __restrict__ x,
    const float* __restrict__ w, const float* __restrict__ bv,
    __hip_bfloat16* __restrict__ B1t) {
  __shared__ float hs[16][262];
  int blk = blockIdx.x, bb = blk >> 5, g = blk & 31;
  size_t base = ((size_t)bb * Cc + g * 16) * Tt;
  const float* xp = x + base;
  float s = 0.f, ss = 0.f;
  for (int i = TID * 4; i < 16 * Tt; i += 1024) {
    float4 v = *reinterpret_cast<const float4*>(xp + i);
    s  += v.x + v.y + v.z + v.w;
    ss += v.x * v.x + v.y * v.y + v.z * v.z + v.w * v.w;
  }
  blockReduce2(s, ss);
  float mean = s * (1.f / 16384.f);
  float rstd = rsqrtf(ss * (1.f / 16384.f) - mean * mean + 1e-5f);

  char* ob = reinterpret_cast<char*>(B1t + (size_t)bb * Tt * 1024 + g * 32);
  for (int tc = 0; tc < 4; ++tc) {
    int tbase = tc * 256;
    __syncthreads();
    for (int task = TID; task < 1024; task += 256) {
      int row = task >> 6, c4 = task & 63;
      int ch = g * 16 + row;
      float sw = w[ch] * rstd;
      float sb = bv[ch] - mean * sw;
      float4 v = *reinterpret_cast<const float4*>(xp + (size_t)row * Tt + tbase + c4 * 4);
      hs[row][c4 * 4 + 0] = v.x * sw + sb;
      hs[row][c4 * 4 + 1] = v.y * sw + sb;
      hs[row][c4 * 4 + 2] = v.z * sw + sb;
      hs[row][c4 * 4 + 3] = v.w * sw + sb;
    }
    if (TID < 16) {  // right halo col 256 <-> t = tbase+256
      int row = TID, t = tbase + 256;
      float val = 0.f;
      if (t < Tt) {
        int ch = g * 16 + row;
        float sw = w[ch] * rstd;
        float sb = bv[ch] - mean * sw;
        val = xp[(size_t)row * Tt + t] * sw + sb;
      }
      hs[row][256] = val;
    }
    __syncthreads();
    for (int task = TID; task < 1024; task += 256) {
      int t = task >> 2, cj = task & 3;
      int ci = cj * 4;
      uint4 u;
      u.x = pack2bf(hs[ci + 0][t], hs[ci + 0][t + 1]);
      u.y = pack2bf(hs[ci + 1][t], hs[ci + 1][t + 1]);
      u.z = pack2bf(hs[ci + 2][t], hs[ci + 2][t + 1]);
      u.w = pack2bf(hs[ci + 3][t], hs[ci + 3][t + 1]);
      *reinterpret_cast<uint4*>(ob + ((size_t)(tbase + t) * 1024 + cj * 8) * 2) = u;
    }
  }
}

// ---------------- im2col(K=4, pad_lo=1) on attn output -> bf16 B4t[b][t][k=4ci+j], coalesced ----------------
__global__ __launch_bounds__(256) void im2col_k4(const float* __restrict__ a,
    __hip_bfloat16* __restrict__ B4t) {
  __shared__ float hs[16][266];
  int bb = blockIdx.x >> 5, cg = blockIdx.x & 31;
  const float* ab = a + ((size_t)bb * Cc + cg * 16) * Tt;
  char* ob = reinterpret_cast<char*>(B4t + (size_t)bb * Tt * 2048 + cg * 64);
  for (int tc = 0; tc < 4; ++tc) {
    int tbase = tc * 256;
    __syncthreads();
    // cols: col j <-> t = tbase + j - 1 (left halo 1, right halo 2; cols 0..258)
    for (int task = TID; task < 1024; task += 256) {
      int row = task >> 6, c4 = task & 63;
      float4 v = *reinterpret_cast<const float4*>(ab + (size_t)row * Tt + tbase + c4 * 4);
      hs[row][c4 * 4 + 1] = v.x;
      hs[row][c4 * 4 + 2] = v.y;
      hs[row][c4 * 4 + 3] = v.z;
      hs[row][c4 * 4 + 4] = v.w;
    }
    if (TID < 48) {
      int row = TID / 3, e = TID % 3;
      int t = (e == 0) ? tbase - 1 : tbase + 256 + (e - 1);
      float v = (t >= 0 && t < Tt) ? ab[(size_t)row * Tt + t] : 0.f;
      int col = (e == 0) ? 0 : 257 + (e - 1);
      hs[row][col] = v;
    }
    __syncthreads();
    for (int task = TID; task < 2048; task += 256) {
      int t = task >> 3, cj = task & 7;
      int ci = cj * 2;
      uint4 u;
      u.x = pack2bf(hs[ci][t],     hs[ci][t + 1]);
      u.y = pack2bf(hs[ci][t + 2], hs[ci][t + 3]);
      u.z = pack2bf(hs[ci + 1][t],     hs[ci + 1][t + 1]);
      u.w = pack2bf(hs[ci + 1][t + 2], hs[ci + 1][t + 3]);
      *reinterpret_cast<uint4*>(ob + ((size_t)(tbase + t) * 2048 + cj * 8) * 2) = u;
    }
  }
}

// ---------------- f32 -> bf16 cast (weights) ----------------
__global__ __launch_bounds__(256) void cast_bf16(const float* __restrict__ in,
    __hip_bfloat16* __restrict__ out, int n) {
  int i = (blockIdx.x * 256 + TID) * 4;
  if (i >= n) return;
  float4 v = *reinterpret_cast<const float4*>(in + i);
  *reinterpret_cast<unsigned int*>(out + i)     = pack2bf(v.x, v.y);
  *reinterpret_cast<unsigned int*>(out + i + 2) = pack2bf(v.z, v.w);
}

// ---------------- bf16 MFMA GEMM: C[b][o][t] = sum_k A[o][k] * Bt[b][t][k] + bias[o] ----------------
template<int K, int MT>
__global__ __launch_bounds__(256) void gemm_bt(const __hip_bfloat16* __restrict__ A,
    const __hip_bfloat16* __restrict__ Bt, const float* __restrict__ bias,
    float* __restrict__ C, int M) {
  constexpr int ACH = (MT / 16) * 2;
  constexpr int NCH = ACH + 16;
  constexpr int NF  = (MT == 128) ? 4 : 2;
  __shared__ __align__(16) char lds[NCH * 1024];
  int t0 = blockIdx.x * 128, o0 = blockIdx.y * MT, bz = blockIdx.z;
  int wave = TID >> 6, lane = TID & 63;
  int l4 = lane >> 4, r15 = lane & 15;
  const __hip_bfloat16* Ab = A + (size_t)o0 * K;
  const __hip_bfloat16* Bb = Bt + ((size_t)bz * 1024 + t0) * K;
  int mbase = (MT == 128) ? (wave >> 1) * 4 : 0;
  int nbase = (MT == 128) ? (wave & 1) * 4 : wave * 2;

  f32x4 acc[4][NF];
  f32x4 zz = {0.f, 0.f, 0.f, 0.f};
  #pragma unroll
  for (int m = 0; m < 4; ++m)
    #pragma unroll
    for (int n = 0; n < NF; ++n) acc[m][n] = zz;

  for (int kt = 0; kt < K / 64; ++kt) {
    #pragma unroll
    for (int c = 0; c < NCH / 4; ++c) {
      int ch = c * 4 + wave;
      int cl = (ch < ACH) ? ch : ch - ACH;
      int row = (cl >> 1) * 16 + r15;
      int kof = kt * 64 + (cl & 1) * 32 + l4 * 8;
      const __hip_bfloat16* src = (ch < ACH) ? (Ab + (size_t)row * K + kof)
                                             : (Bb + (size_t)row * K + kof);
      async16(src, lds + ch * 1024 + lane * 16);
    }
    __syncthreads();
    #pragma unroll
    for (int kk = 0; kk < 2; ++kk) {
      bf16x8 af[4], bfr[NF];
      #pragma unroll
      for (int m = 0; m < 4; ++m)
        af[m] = *reinterpret_cast<const bf16x8*>(lds + ((mbase + m) * 2 + kk) * 1024 + lane * 16);
      #pragma unroll
      for (int n = 0; n < NF; ++n)
        bfr[n] = *reinterpret_cast<const bf16x8*>(lds + (ACH + (nbase + n) * 2 + kk) * 1024 + lane * 16);
      #pragma unroll
      for (int m = 0; m < 4; ++m)
        #pragma unroll
        for (int n = 0; n < NF; ++n)
          acc[m][n] = __builtin_amdgcn_mfma_f32_16x16x32_bf16(af[m], bfr[n], acc[m][n], 0, 0, 0);
    }
    __syncthreads();
  }

  #pragma unroll
  for (int m = 0; m < 4; ++m)
    #pragma unroll
    for (int n = 0; n < NF; ++n) {
      int ocol = t0 + (nbase + n) * 16 + r15;
      #pragma unroll
      for (int r = 0; r < 4; ++r) {
        int orow = o0 + (mbase + m) * 16 + l4 * 4 + r;
        C[((size_t)bz * M + orow) * 1024 + ocol] = acc[m][n][r] + bias[orow];
      }
    }
}

// ---------------- generic GroupNorm stats ----------------
__global__ __launch_bounds__(256) void gn_stats_kernel(const float* __restrict__ x,
    float2* __restrict__ stats, int n) {
  const float* p = x + (size_t)blockIdx.x * n;
  float s = 0.f, ss = 0.f;
  for (int i = TID * 4; i < n; i += 1024) {
    float4 v = *reinterpret_cast<const float4*>(p + i);
    s  += v.x + v.y + v.z + v.w;
    ss += v.x * v.x + v.y * v.y + v.z * v.z + v.w * v.w;
  }
  blockReduce2(s, ss);
  if (TID == 0) {
    float mean = s / (float)n;
    float var = ss / (float)n - mean * mean;
    stats[blockIdx.x] = make_float2(mean, rsqrtf(var + 1e-5f));
  }
}

// ---------------- fused GN(8)+Mish + build attn input images ----------------
// Per block: one (hb, 64-tile). Emits:
//   qTp  [hb][tl][t][c]   bf16, plain chunks (read direct to regs)
//   kimg [hb][tl][s][c]   bf16, chunk swizzle (c>>3)^(s&7)  (LDS image)
//   vimg [hb][tl][c][s]   bf16, chunk swizzle (s>>3)^(c&7)  (LDS image)
__global__ __launch_bounds__(256) void gn2_prep(const float* __restrict__ qkv,
    const float2* __restrict__ st, const float* __restrict__ w, const float* __restrict__ bv,
    char* __restrict__ qTp, char* __restrict__ kimg, char* __restrict__ vimg) {
  __shared__ unsigned short hbf[192 * 66];
  int tl = blockIdx.x & 15, hb = blockIdx.x >> 4;
  int b = hb >> 3, hd = hb & 7;
  const float* base = qkv + ((size_t)b * C3 + hd * 192) * Tt + tl * 64;
  float2 ms = st[b * 8 + hd];
  // phase A: normalize+mish -> bf16 LDS [192 rows][64 t], row stride 66
  for (int task = TID; task < 768; task += 256) {
    int row = task >> 2, seg = task & 3;
    int ch = hd * 192 + row;
    float sw = w[ch] * ms.y;
    float sb = bv[ch] - ms.x * sw;
    const float* src = base + (size_t)row * Tt + seg * 16;
    unsigned int* dst = reinterpret_cast<unsigned int*>(&hbf[row * 66 + seg * 16]);
    #pragma unroll
    for (int q4 = 0; q4 < 4; ++q4) {
      float4 v = *reinterpret_cast<const float4*>(src + q4 * 4);
      dst[q4 * 2]     = pack2bf(mishf(v.x * sw + sb), mishf(v.y * sw + sb));
      dst[q4 * 2 + 1] = pack2bf(mishf(v.z * sw + sb), mishf(v.w * sw + sb));
    }
  }
  __syncthreads();
  size_t tileof = ((size_t)hb * 16 + tl) * 8192;
  // phase B1: Q^T (no swizzle) + K^T (swizzled)
  {
    int t = TID & 63, sel = TID >> 6;
    int img = sel >> 1, half = sel & 1;
    char* obase = (img == 0 ? qTp : kimg) + tileof + (size_t)t * 128;
    #pragma unroll
    for (int cc = 0; cc < 4; ++cc) {
      int chunk = half * 4 + cc;
      uint4 u;
      unsigned int* up = reinterpret_cast<unsigned int*>(&u);
      #pragma unroll
      for (int j = 0; j < 4; ++j) {
        int c = chunk * 8 + j * 2;
        unsigned int lo = hbf[(img * 64 + c) * 66 + t];
        unsigned int hi = hbf[(img * 64 + c + 1) * 66 + t];
        up[j] = lo | (hi << 16);
      }
      int cpos = (img == 0) ? chunk : (chunk ^ (t & 7));
      *reinterpret_cast<uint4*>(obase + cpos * 16) = u;
    }
  }
  // phase B2: V (swizzled, no transpose)
  {
    int c = TID & 63, qtr = TID >> 6;
    const unsigned int* vrow = reinterpret_cast<const unsigned int*>(&hbf[(128 + c) * 66]);
    char* obase = vimg + tileof + (size_t)c * 128;
    #pragma unroll
    for (int k = 0; k < 2; ++k) {
      int chunk = qtr * 2 + k;
      uint4 u;
      unsigned int* up = reinterpret_cast<unsigned int*>(&u);
      #pragma unroll
      for (int j = 0; j < 4; ++j) up[j] = vrow[chunk * 4 + j];
      *reinterpret_cast<uint4*>(obase + (chunk ^ (c & 7)) * 16) = u;
    }
  }
}

// ---------------- MFMA flash attention v2: async-staged images, double-buffered ----------------
__global__ __launch_bounds__(256) void attn_mfma2(const char* __restrict__ qTp,
    const char* __restrict__ kimg, const char* __restrict__ vimg,
    float* __restrict__ a) {
  __shared__ __align__(16) char smem[40960];
  char* kbuf0 = smem;
  char* kbuf1 = smem + 8192;
  char* vbuf0 = smem + 16384;
  char* vbuf1 = smem + 24576;
  char* pp    = smem + 32768;
  char* ov    = smem;  // 16KB alias over kbuf0+kbuf1 (dead after loop)

  int tl = blockIdx.x, hb = blockIdx.y;
  int b = hb >> 3, hd = hb & 7;
  int lane = TID & 63, wave = TID >> 6;
  int l4 = lane >> 4, r15 = lane & 15;
  size_t ibase = (size_t)hb * 16 * 8192;
  const char* ksrc = kimg + ibase;
  const char* vsrc = vimg + ibase;

  // stage s-tile 0
  #pragma unroll
  for (int j = 0; j < 2; ++j) {
    int u = j * 256 + TID;
    async16(ksrc + u * 16, kbuf0 + u * 16);
    async16(vsrc + u * 16, vbuf0 + u * 16);
  }
  // Q fragments direct global -> regs
  bf16x8 aq[2];
  int tg = wave * 16 + r15;
  const char* qrow = qTp + ibase + (size_t)tl * 8192 + (size_t)tg * 128;
  aq[0] = *reinterpret_cast<const bf16x8*>(qrow + l4 * 16);
  aq[1] = *reinterpret_cast<const bf16x8*>(qrow + 64 + l4 * 16);

  f32x4 osum[4];
  f32x4 zz = {0.f, 0.f, 0.f, 0.f};
  #pragma unroll
  for (int cf = 0; cf < 4; ++cf) osum[cf] = zz;
  float mrow[4] = {-1e30f, -1e30f, -1e30f, -1e30f};
  float lrow[4] = {0.f, 0.f, 0.f, 0.f};
  __syncthreads();

  for (int it = 0; it < 16; ++it) {
    char* kcur = (it & 1) ? kbuf1 : kbuf0;
    char* vcur = (it & 1) ? vbuf1 : vbuf0;
    if (it < 15) {
      char* knxt = (it & 1) ? kbuf0 : kbuf1;
      char* vnxt = (it & 1) ? vbuf0 : vbuf1;
      const char* kn = ksrc + (size_t)(it + 1) * 8192;
      const char* vn = vsrc + (size_t)(it + 1) * 8192;
      #pragma unroll
      for (int j = 0; j < 2; ++j) {
        int u = j * 256 + TID;
        async16(kn + u * 16, knxt + u * 16);
        async16(vn + u * 16, vnxt + u * 16);
      }
    }
    // QK^T: per wave 16t x 64s
    f32x4 sc[4];
    #pragma unroll
    for (int sf = 0; sf < 4; ++sf) sc[sf] = zz;
    #pragma unroll
    for (int sf = 0; sf < 4; ++sf) {
      int sr = sf * 16 + r15;
      #pragma unroll
      for (int kk = 0; kk < 2; ++kk) {
        bf16x8 bk = *reinterpret_cast<const bf16x8*>(kcur + sr * 128 + (((kk * 4 + l4) ^ (sr & 7)) << 4));
        sc[sf] = __builtin_amdgcn_mfma_f32_16x16x32_bf16(aq[kk], bk, sc[sf], 0, 0, 0);
      }
    }
    // online softmax (scale 0.125 inside exp); rows = l4*4+r
    float tmax[4];
    #pragma unroll
    for (int r = 0; r < 4; ++r)
      tmax[r] = fmaxf(fmaxf(sc[0][r], sc[1][r]), fmaxf(sc[2][r], sc[3][r]));
    #pragma unroll
    for (int off = 1; off < 16; off <<= 1)
      #pragma unroll
      for (int r = 0; r < 4; ++r) tmax[r] = fmaxf(tmax[r], __shfl_xor(tmax[r], off));
    float alpha[4];
    #pragma unroll
    for (int r = 0; r < 4; ++r) {
      float mnew = fmaxf(mrow[r], tmax[r]);
      alpha[r] = __expf((mrow[r] - mnew) * 0.125f);
      mrow[r] = mnew;
      lrow[r] *= alpha[r];
    }
    #pragma unroll
    for (int cf = 0; cf < 4; ++cf)
      #pragma unroll
      for (int r = 0; r < 4; ++r) osum[cf][r] *= alpha[r];
    char* pw = pp + wave * 2048;
    float psum[4] = {0.f, 0.f, 0.f, 0.f};
    #pragma unroll
    for (int sf = 0; sf < 4; ++sf) {
      int s = sf * 16 + r15;
      #pragma unroll
      for (int r = 0; r < 4; ++r) {
        float p = __expf((sc[sf][r] - mrow[r]) * 0.125f);
        psum[r] += p;
        int tlc = l4 * 4 + r;
        *reinterpret_cast<__hip_bfloat16*>(pw + tlc * 128 + ((((s >> 3) ^ (tlc & 7)) << 4) | ((s & 7) * 2)))
            = __float2bfloat16(p);
      }
    }
    #pragma unroll
    for (int r = 0; r < 4; ++r) lrow[r] += psum[r];
    asm volatile("s_waitcnt lgkmcnt(0)" ::: "memory");
    __builtin_amdgcn_sched_barrier(0);

    // PV
    bf16x8 pa[2];
    #pragma unroll
    for (int kk = 0; kk < 2; ++kk)
      pa[kk] = *reinterpret_cast<const bf16x8*>(pw + r15 * 128 + (((kk * 4 + l4) ^ (r15 & 7)) << 4));
    #pragma unroll
    for (int cf = 0; cf < 4; ++cf) {
      int cr = cf * 16 + r15;
      #pragma unroll
      for (int kk = 0; kk < 2; ++kk) {
        bf16x8 bv = *reinterpret_cast<const bf16x8*>(vcur + cr * 128 + (((kk * 4 + l4) ^ (cr & 7)) << 4));
        osum[cf] = __builtin_amdgcn_mfma_f32_16x16x32_bf16(pa[kk], bv, osum[cf], 0, 0, 0);
      }
    }
    __syncthreads();
  }

  #pragma unroll
  for (int off = 1; off < 16; off <<= 1)
    #pragma unroll
    for (int r = 0; r < 4; ++r) lrow[r] += __shfl_xor(lrow[r], off);
  float linv[4];
  #pragma unroll
  for (int r = 0; r < 4; ++r) linv[r] = 1.f / lrow[r];

  // write O to ov[c][t] f32 (chunk-swizzled), then coalesced global store
  #pragma unroll
  for (int cf = 0; cf < 4; ++cf) {
    int c = cf * 16 + r15;
    #pragma unroll
    for (int r = 0; r < 4; ++r) {
      int t = wave * 16 + l4 * 4 + r;
      *reinterpret_cast<float*>(ov + c * 256 + ((((t >> 2) ^ (c & 7)) << 4) | ((t & 3) * 4)))
          = osum[cf][r] * linv[r];
    }
  }
  __syncthreads();
  float* ap = a + ((size_t)b * Cc + hd * 64) * Tt + tl * 64;
  for (int u = TID; u < 1024; u += 256) {
    int c = u >> 4, tq = u & 15;
    float4 o4 = *reinterpret_cast<const float4*>(ov + c * 256 + ((tq ^ (c & 7)) << 4));
    *reinterpret_cast<float4*>(ap + (size_t)c * Tt + tq * 4) = o4;
  }
}

// ---------------- final: out = x + mish(gn(y2)) in-place on d_out ----------------
__global__ __launch_bounds__(256) void final_kernel(const float* __restrict__ x,
    float* __restrict__ y, const float2* __restrict__ st,
    const float* __restrict__ w, const float* __restrict__ bv) {
  size_t i = ((size_t)blockIdx.x * 256 + TID) * 4;
  int ch = (int)((i >> 10) & (Cc - 1));
  int b = (int)(i >> 19);
  float2 ms = st[b * 8 + (ch >> 6)];
  float sw = w[ch] * ms.y;
  float sb = bv[ch] - ms.x * sw;
  float4 v  = *reinterpret_cast<const float4*>(y + i);
  float4 xv = *reinterpret_cast<const float4*>(x + i);
  v.x = xv.x + mishf(v.x * sw + sb);
  v.y = xv.y + mishf(v.y * sw + sb);
  v.z = xv.z + mishf(v.z * sw + sb);
  v.w = xv.w + mishf(v.w * sw + sb);
  *reinterpret_cast<float4*>(y + i) = v;
}

extern "C" void kernel_launch(void* const* d_in, const int* in_sizes, int n_in,
                              void* d_out, int out_size, void* d_ws, size_t ws_size,
                              hipStream_t stream) {
  const float* x     = (const float*)d_in[0];
  const float* gn_w  = (const float*)d_in[1];
  const float* gn_b  = (const float*)d_in[2];
  const float* wqkv  = (const float*)d_in[3];
  const float* bqkv  = (const float*)d_in[4];
  const float* gnq_w = (const float*)d_in[5];
  const float* gnq_b = (const float*)d_in[6];
  const float* wproj = (const float*)d_in[7];
  const float* bproj = (const float*)d_in[8];
  const float* gnp_w = (const float*)d_in[9];
  const float* gnp_b = (const float*)d_in[10];
  float* out = (float*)d_out;

  char* ws = (char*)d_ws;
  const size_t MB = 1024 * 1024;
  // Time-multiplexed workspace (<= 64MB):
  float* qkv = (float*)ws;                               // [0,48MB)   step3 -> step5
  float* hbuf = (float*)ws;                              // [0,16MB)   step6 -> step7 (qkv dead)
  __hip_bfloat16* B4t = (__hip_bfloat16*)(ws + 16 * MB); // [16,48MB)  step7 -> step9
  __hip_bfloat16* A1  = (__hip_bfloat16*)(ws + 48 * MB); // [48,51MB)  step1 -> step3
  char* vimg = ws + 48 * MB;                             // [48,56MB)  step5 -> step6 (A1 dead)
  __hip_bfloat16* A2  = (__hip_bfloat16*)(ws + 48 * MB); // [48,50MB)  step8 -> step9 (vimg dead)
  float2* st2 = (float2*)(ws + 63 * MB);
  float2* st3 = st2 + 64;
  __hip_bfloat16* B1t = (__hip_bfloat16*)d_out;          // d_out as B1t  step2 -> step3
  char* qTp  = (char*)d_out;                             // d_out[0,8MB)  step5 -> step6
  char* kimg = (char*)d_out + 8 * MB;                    // d_out[8,16MB) step5 -> step6

  dim3 blk(256);
  cast_bf16<<<1536, blk, 0, stream>>>(wqkv, A1, C3 * 1024);                      // 1
  gn1_im2col<<<256, blk, 0, stream>>>(x, gn_w, gn_b, B1t);                       // 2
  gemm_bt<1024, 128><<<dim3(8, 12, 8), blk, 0, stream>>>(A1, B1t, bqkv, qkv, C3);// 3
  gn_stats_kernel<<<64, blk, 0, stream>>>(qkv, st2, 192 * 1024);                 // 4
  gn2_prep<<<1024, blk, 0, stream>>>(qkv, st2, gnq_w, gnq_b, qTp, kimg, vimg);   // 5
  attn_mfma2<<<dim3(16, 64), blk, 0, stream>>>(qTp, kimg, vimg, hbuf);           // 6
  im2col_k4<<<256, blk, 0, stream>>>(hbuf, B4t);                                 // 7
  cast_bf16<<<1024, blk, 0, stream>>>(wproj, A2, Cc * 2048);                     // 8
  gemm_bt<2048, 64><<<dim3(8, 8, 8), blk, 0, stream>>>(A2, B4t, bproj, out, Cc); // 9
  gn_stats_kernel<<<64, blk, 0, stream>>>(out, st3, 64 * 1024);                  // 10
  final_kernel<<<4096, blk, 0, stream>>>(x, out, st3, gnp_w, gnp_b);             // 11
}